// Round 8
// baseline (789.491 us; speedup 1.0000x reference)
//
#include <hip/hip_runtime.h>
#include <math.h>

#define D_IN 512
#define F1   16
#define F2   7

typedef float vf4 __attribute__((ext_vector_type(4)));  // clang vectors: nontemporal-load OK
typedef int   vi4 __attribute__((ext_vector_type(4)));

// ---- P1: in-degree histogram (fire-and-forget global atomics, deg table L2-resident) ----
__global__ __launch_bounds__(256) void deg_kernel(const int* __restrict__ dst,
                                                  int* __restrict__ deg, int E) {
    int i = (blockIdx.x * 256 + threadIdx.x) * 4;
    if (i + 4 <= E) {
        vi4 d = __builtin_nontemporal_load((const vi4*)(dst + i));
        atomicAdd(&deg[d[0]], 1);
        atomicAdd(&deg[d[1]], 1);
        atomicAdd(&deg[d[2]], 1);
        atomicAdd(&deg[d[3]], 1);
    } else {
        for (; i < E; ++i) atomicAdd(&deg[dst[i]], 1);
    }
}

// ---- P2a: per-block (512 nodes) degree sums ----
__global__ __launch_bounds__(512) void degsum_kernel(const int* __restrict__ deg,
                                                     int* __restrict__ bsum, int n) {
    __shared__ int sm[512];
    int t = threadIdx.x;
    int i = blockIdx.x * 512 + t;
    sm[t] = i < n ? deg[i] : 0;
    __syncthreads();
    for (int off = 256; off; off >>= 1) {
        if (t < off) sm[t] += sm[t + off];
        __syncthreads();
    }
    if (t == 0) bsum[blockIdx.x] = sm[0];
}

// ---- P2b: exclusive scan of block sums (NBLK <= 256 for n <= 131072) ----
__global__ __launch_bounds__(256) void bscan_kernel(int* __restrict__ bsum, int NBLK) {
    __shared__ int sm[256];
    int t = threadIdx.x;
    int v = t < NBLK ? bsum[t] : 0;
    sm[t] = v;
    __syncthreads();
    for (int off = 1; off < 256; off <<= 1) {
        int u = (t >= off) ? sm[t - off] : 0;
        __syncthreads();
        sm[t] += u;
        __syncthreads();
    }
    if (t < NBLK) bsum[t] = sm[t] - v;   // exclusive
}

// ---- P2c: per-node row_ptr/row_end/dinv; cursor := row_ptr (in-place over deg) ----
__global__ __launch_bounds__(512) void rowptr_kernel(int* __restrict__ deg_cursor,
                                                     const int* __restrict__ bsum,
                                                     int* __restrict__ row_ptr,
                                                     int* __restrict__ row_end,
                                                     float* __restrict__ dinv, int n) {
    __shared__ int sm[512];
    int t = threadIdx.x;
    int i = blockIdx.x * 512 + t;
    int d = i < n ? deg_cursor[i] : 0;
    sm[t] = d;
    __syncthreads();
    for (int off = 1; off < 512; off <<= 1) {
        int u = (t >= off) ? sm[t - off] : 0;
        __syncthreads();
        sm[t] += u;
        __syncthreads();
    }
    if (i < n) {
        int ex = sm[t] - d + bsum[blockIdx.x];
        row_ptr[i] = ex;
        row_end[i] = ex + d;
        dinv[i] = rsqrtf((float)d + 1.0f);
        deg_cursor[i] = ex;   // alloc cursor for scatter
    }
}

// ---- P3: CSR scatter: adj[atomicAdd(cursor[dst])] = src ----
// cursor is 400KB L2-resident; adj writes are random 4B but densely fill the
// 12.8MB region -> dirty-byte merge in L2/HBM. Order within a row arbitrary
// (aggregation is order-independent, matching the old atomic-cursor design).
__global__ __launch_bounds__(256) void scatter_kernel(const int* __restrict__ src,
                                                      const int* __restrict__ dst,
                                                      int* __restrict__ cursor,
                                                      int* __restrict__ adj, int E) {
    int i = (blockIdx.x * 256 + threadIdx.x) * 4;
    if (i + 4 <= E) {
        vi4 s = __builtin_nontemporal_load((const vi4*)(src + i));
        vi4 d = __builtin_nontemporal_load((const vi4*)(dst + i));
        int p0 = atomicAdd(&cursor[d[0]], 1); adj[p0] = s[0];
        int p1 = atomicAdd(&cursor[d[1]], 1); adj[p1] = s[1];
        int p2 = atomicAdd(&cursor[d[2]], 1); adj[p2] = s[2];
        int p3 = atomicAdd(&cursor[d[3]], 1); adj[p3] = s[3];
    } else {
        for (; i < E; ++i) {
            int p = atomicAdd(&cursor[dst[i]], 1);
            adj[p] = src[i];
        }
    }
}

// ---- layer-1 matmul: h1s = (x @ W1) * dinv[node] ----
// One wave = one node per iteration; W1 register-resident per lane (K-slice
// {4l..4l+3} u {256+4l..+3}); two dense dwordx4 loads per node; feature-
// splitting butterfly leaves feature f in lane f. (round-4 verified, 192->~50us)
__global__ __launch_bounds__(256, 2) void mm1_kernel(const float* __restrict__ x,
                                                     const float* __restrict__ W1,
                                                     const float* __restrict__ dinv,
                                                     float* __restrict__ h1s, int n) {
    int tid = threadIdx.x;
    int lane = tid & 63;
    int wid  = blockIdx.x * 4 + (tid >> 6);   // global wave id
    int nwaves = gridDim.x * 4;

    // preload W1 rows kA = 4*lane + r and kB = 256 + 4*lane + r (r=0..3)
    float wA[4][16], wB[4][16];
#pragma unroll
    for (int r = 0; r < 4; ++r) {
        const float4* ra = (const float4*)(W1 + (size_t)(4 * lane + r) * F1);
        const float4* rb = (const float4*)(W1 + (size_t)(256 + 4 * lane + r) * F1);
#pragma unroll
        for (int q = 0; q < 4; ++q) {
            float4 va = ra[q], vb = rb[q];
            wA[r][4 * q + 0] = va.x; wA[r][4 * q + 1] = va.y;
            wA[r][4 * q + 2] = va.z; wA[r][4 * q + 3] = va.w;
            wB[r][4 * q + 0] = vb.x; wB[r][4 * q + 1] = vb.y;
            wB[r][4 * q + 2] = vb.z; wB[r][4 * q + 3] = vb.w;
        }
    }

    int node = wid;
    if (node >= n) return;
    const float* xb = x + (size_t)node * D_IN;
    vf4 pA = *(const vf4*)(xb + 4 * lane);          // k = 4l..4l+3
    vf4 pB = *(const vf4*)(xb + 256 + 4 * lane);    // k = 256+4l..+3

    while (node < n) {
        vf4 xA = pA, xB = pB;
        int nx = node + nwaves;
        if (nx < n) {                                // prefetch next row (wave-uniform branch)
            const float* xn = x + (size_t)nx * D_IN;
            pA = *(const vf4*)(xn + 4 * lane);
            pB = *(const vf4*)(xn + 256 + 4 * lane);
        }
        float acc[16];
#pragma unroll
        for (int f = 0; f < 16; ++f) acc[f] = 0.f;
#pragma unroll
        for (int r = 0; r < 4; ++r) {
            float ea = xA[r], eb = xB[r];
#pragma unroll
            for (int f = 0; f < 16; ++f) {
                acc[f] += ea * wA[r][f];
                acc[f] += eb * wB[r][f];
            }
        }
        // butterfly: stage s splits features by bit s == lane bit s -> lane f holds feature f
        int h0 = lane & 1, h1 = lane & 2, h2 = lane & 4, h3 = lane & 8;
        float a[8];
#pragma unroll
        for (int j = 0; j < 8; ++j) {
            float keep = h0 ? acc[2 * j + 1] : acc[2 * j];
            float give = h0 ? acc[2 * j] : acc[2 * j + 1];
            a[j] = keep + __shfl_xor(give, 1);
        }
        float b[4];
#pragma unroll
        for (int j = 0; j < 4; ++j) {
            float keep = h1 ? a[2 * j + 1] : a[2 * j];
            float give = h1 ? a[2 * j] : a[2 * j + 1];
            b[j] = keep + __shfl_xor(give, 2);
        }
        float c[2];
#pragma unroll
        for (int j = 0; j < 2; ++j) {
            float keep = h2 ? b[2 * j + 1] : b[2 * j];
            float give = h2 ? b[2 * j] : b[2 * j + 1];
            c[j] = keep + __shfl_xor(give, 4);
        }
        float d = (h3 ? c[1] : c[0]) + __shfl_xor(h3 ? c[0] : c[1], 8);
        d += __shfl_xor(d, 16);
        d += __shfl_xor(d, 32);
        if (lane < 16) {
            float di = dinv[node];
            h1s[(size_t)node * F1 + lane] = d * di;   // 64B contiguous store
        }
        node = nx;
    }
}

// ---- layer-1 gather + fused finalize + FUSED mm2 (round-6 verified) ----
// 16 lanes/node = (e4 edge-slice 0..3) x (jq float4 feature-quarter 0..3).
__global__ __launch_bounds__(256) void agg1_kernel(const int* __restrict__ row_ptr,
                                                   const int* __restrict__ row_end,
                                                   const int* __restrict__ adj,
                                                   const float* __restrict__ h,
                                                   const float* __restrict__ dinv,
                                                   const float* __restrict__ b1,
                                                   const float* __restrict__ W2,
                                                   float* __restrict__ h2s, int n) {
    int t = blockIdx.x * 256 + threadIdx.x;
    int node = t >> 4;
    if (node >= n) return;
    int li = t & 15;
    int jq = li & 3;
    int e4 = li >> 2;
    int s = row_ptr[node], e = row_end[node];
    vf4 a0 = {0.f, 0.f, 0.f, 0.f}, a1 = {0.f, 0.f, 0.f, 0.f};
    int k = s + e4;
    for (; k + 4 < e; k += 8) {
        int s0 = adj[k], s1 = adj[k + 4];
        a0 += *(const vf4*)(h + (size_t)s0 * F1 + jq * 4);
        a1 += *(const vf4*)(h + (size_t)s1 * F1 + jq * 4);
    }
    if (k < e) a0 += *(const vf4*)(h + (size_t)adj[k] * F1 + jq * 4);
    vf4 sum = a0 + a1;
#pragma unroll
    for (int q = 0; q < 4; ++q) {
        sum[q] += __shfl_xor(sum[q], 4, 16);
        sum[q] += __shfl_xor(sum[q], 8, 16);
    }
    float di = dinv[node];
    vf4 self = *(const vf4*)(h + (size_t)node * F1 + jq * 4);
    float v0 = di * (sum[0] + self[0]) + b1[jq * 4 + 0]; v0 = v0 > 0.f ? v0 : 0.f;
    float v1 = di * (sum[1] + self[1]) + b1[jq * 4 + 1]; v1 = v1 > 0.f ? v1 : 0.f;
    float v2 = di * (sum[2] + self[2]) + b1[jq * 4 + 2]; v2 = v2 > 0.f ? v2 : 0.f;
    float v3 = di * (sum[3] + self[3]) + b1[jq * 4 + 3]; v3 = v3 > 0.f ? v3 : 0.f;
    // mm2 partials: this lane's 4 features x W2 rows jq*4..jq*4+3
    const float* w0 = W2 + (size_t)(jq * 4 + 0) * F2;
    const float* w1 = W2 + (size_t)(jq * 4 + 1) * F2;
    const float* w2 = W2 + (size_t)(jq * 4 + 2) * F2;
    const float* w3 = W2 + (size_t)(jq * 4 + 3) * F2;
    float p0 = v0 * w0[0] + v1 * w1[0] + v2 * w2[0] + v3 * w3[0];
    float p1 = v0 * w0[1] + v1 * w1[1] + v2 * w2[1] + v3 * w3[1];
    float p2 = v0 * w0[2] + v1 * w1[2] + v2 * w2[2] + v3 * w3[2];
    float p3 = v0 * w0[3] + v1 * w1[3] + v2 * w2[3] + v3 * w3[3];
    float p4 = v0 * w0[4] + v1 * w1[4] + v2 * w2[4] + v3 * w3[4];
    float p5 = v0 * w0[5] + v1 * w1[5] + v2 * w2[5] + v3 * w3[5];
    float p6 = v0 * w0[6] + v1 * w1[6] + v2 * w2[6] + v3 * w3[6];
    // reduce over jq (lane bits 0-1)
    p0 += __shfl_xor(p0, 1, 16); p0 += __shfl_xor(p0, 2, 16);
    p1 += __shfl_xor(p1, 1, 16); p1 += __shfl_xor(p1, 2, 16);
    p2 += __shfl_xor(p2, 1, 16); p2 += __shfl_xor(p2, 2, 16);
    p3 += __shfl_xor(p3, 1, 16); p3 += __shfl_xor(p3, 2, 16);
    p4 += __shfl_xor(p4, 1, 16); p4 += __shfl_xor(p4, 2, 16);
    p5 += __shfl_xor(p5, 1, 16); p5 += __shfl_xor(p5, 2, 16);
    p6 += __shfl_xor(p6, 1, 16); p6 += __shfl_xor(p6, 2, 16);
    if (li < 8) {
        float oc = li == 0 ? p0 : li == 1 ? p1 : li == 2 ? p2 : li == 3 ? p3
                 : li == 4 ? p4 : li == 5 ? p5 : li == 6 ? p6 : 0.0f;
        h2s[(size_t)node * 8 + li] = oc * di;
    }
}

// ---- layer-2 gather + fused bias/self-loop/log_softmax -> out (round-6 verified) ----
__global__ __launch_bounds__(256) void agg2_kernel(const int* __restrict__ row_ptr,
                                                   const int* __restrict__ row_end,
                                                   const int* __restrict__ adj,
                                                   const float* __restrict__ h,
                                                   const float* __restrict__ dinv,
                                                   const float* __restrict__ b2,
                                                   float* __restrict__ out, int n) {
    int t = blockIdx.x * 256 + threadIdx.x;
    int node = t >> 3;
    if (node >= n) return;
    int li = t & 7;
    int jh = li & 1;
    int e4 = li >> 1;
    int s = row_ptr[node], e = row_end[node];
    vf4 a0 = {0.f, 0.f, 0.f, 0.f}, a1 = {0.f, 0.f, 0.f, 0.f};
    int k = s + e4;
    for (; k + 4 < e; k += 8) {
        int s0 = adj[k], s1 = adj[k + 4];
        a0 += *(const vf4*)(h + (size_t)s0 * 8 + jh * 4);
        a1 += *(const vf4*)(h + (size_t)s1 * 8 + jh * 4);
    }
    if (k < e) a0 += *(const vf4*)(h + (size_t)adj[k] * 8 + jh * 4);
    vf4 sum = a0 + a1;
#pragma unroll
    for (int q = 0; q < 4; ++q) {
        sum[q] += __shfl_xor(sum[q], 2, 8);
        sum[q] += __shfl_xor(sum[q], 4, 8);
    }
    float di = dinv[node];
    vf4 self = *(const vf4*)(h + (size_t)node * 8 + jh * 4);
    float v0 = di * (sum[0] + self[0]) + (jh ? b2[4] : b2[0]);
    float v1 = di * (sum[1] + self[1]) + (jh ? b2[5] : b2[1]);
    float v2 = di * (sum[2] + self[2]) + (jh ? b2[6] : b2[2]);
    float v3 = jh ? -INFINITY : di * (sum[3] + self[3]) + b2[3];
    float m4 = fmaxf(fmaxf(v0, v1), fmaxf(v2, v3));
    float m = fmaxf(m4, __shfl_xor(m4, 1, 8));
    float es = expf(v0 - m) + expf(v1 - m) + expf(v2 - m) + (jh ? 0.f : expf(v3 - m));
    float ssum = es + __shfl_xor(es, 1, 8);
    float lse = m + logf(ssum);
    float* op = out + (size_t)node * F2 + jh * 4;
    op[0] = v0 - lse; op[1] = v1 - lse; op[2] = v2 - lse;
    if (!jh) op[3] = v3 - lse;
}

extern "C" void kernel_launch(void* const* d_in, const int* in_sizes, int n_in,
                              void* d_out, int out_size, void* d_ws, size_t ws_size,
                              hipStream_t stream) {
    const float* x  = (const float*)d_in[0];
    const int*   ei = (const int*)d_in[1];
    const float* W1 = (const float*)d_in[2];
    const float* b1 = (const float*)d_in[3];
    const float* W2 = (const float*)d_in[4];
    const float* b2 = (const float*)d_in[5];

    int n = in_sizes[0] / D_IN;
    int E = in_sizes[1] / 2;
    const int* src = ei;
    const int* dst = ei + E;
    int NBLK = (n + 511) >> 9;          // <=256 for n<=131072

    // workspace layout (4-byte elements)
    char* ws = (char*)d_ws;
    size_t o = 0;
    int*   row_ptr = (int*)(ws + o);   o += (size_t)n * 4;
    int*   row_end = (int*)(ws + o);   o += (size_t)n * 4;
    float* dinv    = (float*)(ws + o); o += (size_t)n * 4;
    int*   cursor  = (int*)(ws + o);   o += (size_t)n * 4;   // deg accumulator, then alloc cursor
    int*   bsum    = (int*)(ws + o);   o += 256 * 4;
    int*   adj     = (int*)(ws + o);   o += (size_t)E * 4;
    float* h1s     = (float*)(ws + o); o += (size_t)n * F1 * 4;
    float* h2s     = (float*)(ws + o); o += (size_t)n * 8 * 4;
    float* out = (float*)d_out;

    const int B = 256;
    int GE = (E + 1023) / 1024;         // 4 edges/thread

    hipMemsetAsync(cursor, 0, (size_t)n * sizeof(int), stream);

    deg_kernel<<<GE, B, 0, stream>>>(dst, cursor, E);
    degsum_kernel<<<NBLK, 512, 0, stream>>>(cursor, bsum, n);
    bscan_kernel<<<1, 256, 0, stream>>>(bsum, NBLK);
    rowptr_kernel<<<NBLK, 512, 0, stream>>>(cursor, bsum, row_ptr, row_end, dinv, n);
    scatter_kernel<<<GE, B, 0, stream>>>(src, dst, cursor, adj, E);

    mm1_kernel<<<512, B, 0, stream>>>(x, W1, dinv, h1s, n);

    agg1_kernel<<<((size_t)n * F1 + B - 1) / B, B, 0, stream>>>(row_ptr, row_end, adj, h1s, dinv, b1, W2, h2s, n);

    agg2_kernel<<<((size_t)n * 8 + B - 1) / B, B, 0, stream>>>(row_ptr, row_end, adj, h2s, dinv, b2, out, n);
}